// Round 15
// baseline (113.837 us; speedup 1.0000x reference)
//
#include <hip/hip_runtime.h>

#define EPSF 1e-9f

constexpr int I   = 144;    // 9*16 input capsules
constexpr int IC  = 36;     // i's per chunk (4 chunks per wave)
constexpr int RT  = 148;    // s_zr row stride (144 + 4 pad)
constexpr int SP  = 20;     // s_pose row stride (16 + 4 pad)
constexpr int QS  = 20;     // s_q row stride (16 o's + 4 pad)

// R20: xor-pattern cross-lane ops moved VALU(DPP) -> DS pipe (ds_swizzle,
// immediate operand, no addr VGPR). Rationale: VALU issue is the bottleneck
// (71% busy, ~2800 VALU vs ~120 DS ops/lane); each {dpp_mov+add} pair becomes
// {swizzle(DS)+add(VALU)} = -1 VALU inst x ~250 sites. ror4/ror8 ladders are
// replaced by xor4/xor8 (both sum all 16 lanes; both preserve pc = lane&3).
// lane^32 crosses the 32-lane swizzle boundary -> keep permlane32_swap (VALU).
// NOTE: the old "DPP not DS" rule (R11) was measured in the 1-block/CU
// regime (~2.75 waves/SIMD, chains unhidden). Current regime: 8 waves/SIMD,
// 4 blocks/CU -> DS latency hides behind wave-switching. Regime test.
// ds_swizzle BitMode: offset = (xor<<10)|(or<<5)|and, and=0x1F.
__device__ __forceinline__ float swz_xor1(float x) {
    return __int_as_float(__builtin_amdgcn_ds_swizzle(__float_as_int(x), 0x041F));
}
__device__ __forceinline__ float swz_xor2(float x) {
    return __int_as_float(__builtin_amdgcn_ds_swizzle(__float_as_int(x), 0x081F));
}
__device__ __forceinline__ float swz_xor4(float x) {
    return __int_as_float(__builtin_amdgcn_ds_swizzle(__float_as_int(x), 0x101F));
}
__device__ __forceinline__ float swz_xor8(float x) {
    return __int_as_float(__builtin_amdgcn_ds_swizzle(__float_as_int(x), 0x201F));
}
__device__ __forceinline__ float swz_xor16(float x) {
    return __int_as_float(__builtin_amdgcn_ds_swizzle(__float_as_int(x), 0x401F));
}
__device__ __forceinline__ float quad_sum(float x) {
    float y = x + swz_xor1(x);
    return y + swz_xor2(y);
}
__device__ __forceinline__ float quad_max(float x) {
    float y = fmaxf(x, swz_xor1(x));
    return fmaxf(y, swz_xor2(y));
}
// Full sum across the 16-lane row (xor butterfly; xor4/xor8 preserve lane&3).
__device__ __forceinline__ float row_sum16(float x) {
    float y = quad_sum(x);
    y += swz_xor4(y);
    return y + swz_xor8(y);
}
// lane^16 sum: swizzle (within each 32-lane half, lane^16 stays in-half).
__device__ __forceinline__ float add_xor16(float x) {
    return x + swz_xor16(x);
}
// lane^32: not expressible in ds_swizzle -> gfx950 permlane32_swap (VALU).
__device__ __forceinline__ float add_xor32(float x) {
#if __has_builtin(__builtin_amdgcn_permlane32_swap)
    auto r = __builtin_amdgcn_permlane32_swap(__float_as_int(x), __float_as_int(x), false, false);
    return __int_as_float(r[0]) + __int_as_float(r[1]);
#else
    return x + __shfl_xor(x, 32);
#endif
}
// Fast 1/x (v_rcp_f32, ~1 ulp): fine under the 2e-2 absmax threshold.
__device__ __forceinline__ float frcp(float x) { return __builtin_amdgcn_rcpf(x); }
// Raw hardware log2/exp2; EM runs in base-2 domain (ln2 folded once).
__device__ __forceinline__ float flog2(float x) {
#if __has_builtin(__builtin_amdgcn_logf)
    return __builtin_amdgcn_logf(x);
#else
    return __log2f(x);
#endif
}
__device__ __forceinline__ float fexp2(float x) {
#if __has_builtin(__builtin_amdgcn_exp2f)
    return __builtin_amdgcn_exp2f(x);
#else
    return exp2f(x);
#endif
}

#define LN2F     0.69314718056f
#define INV_LN2F 1.44269504089f

// wt[i,o,pc,q] = w[i,o,q,pc]  -> vote loop reads one float4 per (i, lane)
__global__ void transpose_w_kernel(const float* __restrict__ w, float* __restrict__ wt) {
    const int i = blockIdx.x;
    const int t = threadIdx.x;                  // t = o*16 + q*4 + pc
    const float val = w[i * 256 + t];
    const int o = t >> 4, q = (t >> 2) & 3, pc = t & 3;
    wt[i * 256 + o * 16 + pc * 4 + q] = val;
}

// R15 (measured 53.2us dispatch / 108.6us bench, absmax 4.9e-4 — BANKED BEST,
// reproduced R9/R14): 512 thd = 8 waves; wave owns o and o+8; dual ILP chains;
// 64 VGPR (8 waves/SIMD) + ~4-reg spill (~10MB scratch) -> fastest.
// LAW (R15/R16): dur ~ 1/waves-per-SIMD; winning regime is VGPR <= 64; the
// small spill is the correct trade. Occupancy counter unreliable; trust
// VGPR_Count + dur. Residency is maxed (32 waves/CU, 133KB LDS < 160).
// Issue model: ~5000 wave-insts x 2cyc / 4 SIMD x 36 waves/CU ~ 37.5us at
// 100% VALU busy; measured 53.2 at 71% -> cut VALU insts or raise busy.
// R20 (this round): xor-shuffles VALU->DS (see helpers above). ~-250 VALU.
// REFUTED (do not retry):
//  - LDS-residency gating (R4/R5) / 64KB LDS window (R5)
//  - redundant per-wave softmax to cut barriers (R7: +46%)
//  - no-spill high-VGPR, launch_bounds (512,2) (R16: 6 w/SIMD, +26%)
//  - f16 vote packing (R17: hoisted unpacks, 45MB scratch, +33%)
//  - fused log-sigmoid (R18: CORRECTNESS absmax 0.5 — the eps-clamp in
//    log(sigmoid+1e-9) saturates deeply-negative logits, tying inactive o's;
//    keep exact sigmoid + flog2(o_act + EPSF)).
// NOTE (R5): no barrier between vote loop and EM loop (stagger!).
// NOTE (R8): keep the 3-iter EM loop ROLLED (unroll 1) - I-fetch.
template <bool USE_WT>
__global__ __launch_bounds__(512, 4)
void capsule_em_kernel(const float* __restrict__ pose_in,   // [8,14,14,256]
                       const float* __restrict__ act_in,    // [8,14,14,16]
                       const float* __restrict__ wmat,      // wt (transposed) or w
                       const float* __restrict__ beta_v,    // [16]
                       const float* __restrict__ beta_a,    // [16]
                       float* __restrict__ out)             // pose 294912 | act 18432
{
    __shared__ __align__(16) float s_pose[I * SP];   // 11520 B
    __shared__ __align__(16) float s_zr[16 * RT];    //  9472 B  rr' [o][i]
    __shared__ __align__(16) float s_q[I * QS];      // 11520 B  full p-sums [i][o]
    __shared__ __align__(16) float s_iact[I + 4];    //   592 B
    __shared__ float s_Lo[16];                       //    64 B

    const int tid  = threadIdx.x;
    const int wv   = tid >> 6;          // wave id 0..7
    const int lane = tid & 63;
    const int oa   = wv;                // first owned o
    const int ob   = wv + 8;            // second owned o
    const int c    = lane >> 4;
    const int p    = lane & 15;
    const int pr   = p >> 2;
    const int pc   = p & 3;
    const int i0   = c * IC;
    const bool pb0 = pc & 1;
    const bool pb1 = pc & 2;

    const int n   = blockIdx.x;
    const int b   = n / 144;
    const int rem = n - b * 144;
    const int hp  = rem / 12;
    const int wp  = rem - hp * 12;

    // ---- stage pose patch (576 float4) + i_act (144 floats), 512 threads ----
    {
        const int t0 = tid;             // pass 1: all 512
        const int pk = t0 >> 6, l6 = t0 & 63;
        const int ki = pk / 3, kj = pk - ki * 3;
        const float4 val = *reinterpret_cast<const float4*>(
            &pose_in[((b * 14 + hp + ki) * 14 + (wp + kj)) * 256 + l6 * 4]);
        const int i = pk * 16 + (l6 >> 2), e = (l6 & 3) * 4;
        *reinterpret_cast<float4*>(&s_pose[i * SP + e]) = val;
    }
    if (tid < 64) {                     // pass 2: t = tid + 512
        const int t1 = tid + 512;
        const int pk = t1 >> 6, l6 = t1 & 63;
        const int ki = pk / 3, kj = pk - ki * 3;
        const float4 val = *reinterpret_cast<const float4*>(
            &pose_in[((b * 14 + hp + ki) * 14 + (wp + kj)) * 256 + l6 * 4]);
        const int i = pk * 16 + (l6 >> 2), e = (l6 & 3) * 4;
        *reinterpret_cast<float4*>(&s_pose[i * SP + e]) = val;
    }
    if (tid < 144) {
        const int pk = tid >> 4, ic = tid & 15;
        const int ki = pk / 3, kj = pk - ki * 3;
        s_iact[tid] = act_in[((b * 14 + hp + ki) * 14 + (wp + kj)) * 16 + ic];
    }
    __syncthreads();

    // ---- votes for BOTH o's: pose read shared ----
    float va[IC], vb[IC];
    #pragma unroll
    for (int ii = 0; ii < IC; ++ii) {
        const int i = i0 + ii;
        const float4 pv = *reinterpret_cast<const float4*>(&s_pose[i * SP + pr * 4]);
        if (USE_WT) {
            const float4 wa = *reinterpret_cast<const float4*>(&wmat[i * 256 + oa * 16 + pc * 4]);
            const float4 wb = *reinterpret_cast<const float4*>(&wmat[i * 256 + ob * 16 + pc * 4]);
            va[ii] = pv.x * wa.x + pv.y * wa.y + pv.z * wa.z + pv.w * wa.w;
            vb[ii] = pv.x * wb.x + pv.y * wb.y + pv.z * wb.z + pv.w * wb.w;
        } else {
            const float* wba = &wmat[i * 256 + oa * 16 + pc];
            const float* wbb = &wmat[i * 256 + ob * 16 + pc];
            va[ii] = pv.x * wba[0] + pv.y * wba[4] + pv.z * wba[8] + pv.w * wba[12];
            vb[ii] = pv.x * wbb[0] + pv.y * wbb[4] + pv.z * wbb[8] + pv.w * wbb[12];
        }
    }
    // NO barrier here (R5 lesson): waves enter the EM loop staggered.

    const float bva = beta_v[oa], bvb = beta_v[ob];
    const float baa = beta_a[oa], bab = beta_a[ob];

    float mean_a = 0.0f, mean_b = 0.0f, oact_a = 0.0f, oact_b = 0.0f;

    #pragma unroll 1
    for (int it = 0; it < 3; ++it) {
        // -------- M-step: two independent chains, interleaved for ILP --------
        float aSa = 0.0f, a1a = 0.0f, a2a = 0.0f;
        float aSb = 0.0f, a1b = 0.0f, a2b = 0.0f;
        const float* rra = (it == 0) ? &s_iact[i0] : &s_zr[oa * RT + i0];
        const float* rrb = (it == 0) ? &s_iact[i0] : &s_zr[ob * RT + i0];
        #pragma unroll
        for (int jj = 0; jj < 9; ++jj) {
            const float4 r4a = *reinterpret_cast<const float4*>(&rra[jj * 4]);
            const float4 r4b = *reinterpret_cast<const float4*>(&rrb[jj * 4]);
            const float ra[4] = {r4a.x, r4a.y, r4a.z, r4a.w};
            const float rb[4] = {r4b.x, r4b.y, r4b.z, r4b.w};
            #pragma unroll
            for (int k = 0; k < 4; ++k) {
                const float ta = ra[k] * va[jj * 4 + k];
                const float tb = rb[k] * vb[jj * 4 + k];
                aSa += ra[k];  a1a += ta;  a2a += ta * va[jj * 4 + k];
                aSb += rb[k];  a1b += tb;  a2b += tb * vb[jj * 4 + k];
            }
        }
        // cross-chunk sums: lane^16 on DS (swizzle), lane^32 on VALU (permlane)
        aSa = add_xor16(aSa); aSb = add_xor16(aSb);
        a1a = add_xor16(a1a); a1b = add_xor16(a1b);
        a2a = add_xor16(a2a); a2b = add_xor16(a2b);
        aSa = add_xor32(aSa); aSb = add_xor32(aSb);
        a1a = add_xor32(a1a); a1b = add_xor32(a1b);
        a2a = add_xor32(a2a); a2b = add_xor32(a2b);
        if (it == 0) {   // iter-0 rr' = iact/16: fold 1/16 after reduction
            aSa *= 0.0625f; a1a *= 0.0625f; a2a *= 0.0625f;
            aSb *= 0.0625f; a1b *= 0.0625f; a2b *= 0.0625f;
        }

        const float inva = frcp(aSa + EPSF);
        const float invb = frcp(aSb + EPSF);
        mean_a = a1a * inva;
        mean_b = a1b * invb;
        float vara = (a2a - 2.0f * mean_a * a1a + mean_a * mean_a * aSa) * inva;
        float varb = (a2b - 2.0f * mean_b * a1b + mean_b * mean_b * aSb) * invb;
        vara = fmaxf(vara, 0.0f);
        varb = fmaxf(varb, 0.0f);
        // log(sigma+1e-9) == 0.5*log(var+1e-18) -> no sqrt. LOG2 domain.
        const float sl2a = row_sum16(0.5f * flog2(vara + 1e-18f));
        const float sl2b = row_sum16(0.5f * flog2(varb + 1e-18f));

        const float csa = aSa * (16.0f * bva + LN2F * sl2a);
        const float csb = aSb * (16.0f * bvb + LN2F * sl2b);
        const float it2 = INV_LN2F * (1.0f + (float)it);
        oact_a = frcp(1.0f + fexp2(-it2 * (baa - csa)));
        oact_b = frcp(1.0f + fexp2(-it2 * (bab - csb)));

        // ---------------- E-step (skip on last iter) ----------------
        if (it < 2) {
            const float a2fa = INV_LN2F * frcp(2.0f * vara + EPSF);
            const float a2fb = INV_LN2F * frcp(2.0f * varb + EPSF);
            const float b2a  = 2.0f * mean_a * a2fa;
            const float b2b  = 2.0f * mean_b * a2fb;
            const float cqa  = row_sum16(mean_a * mean_a * a2fa);
            const float cqb  = row_sum16(mean_b * mean_b * a2fb);
            const float LoA  = flog2(oact_a + EPSF) - sl2a - cqa;
            const float LoB  = flog2(oact_b + EPSF) - sl2b - cqb;
            if (lane == 0) { s_Lo[oa] = LoA; s_Lo[ob] = LoB; }
            #pragma unroll
            for (int j = 0; j < 9; ++j) {
                float cta[4], ctb[4];
                #pragma unroll
                for (int t = 0; t < 4; ++t) {
                    const float v1 = va[4 * j + t];
                    const float v2 = vb[4 * j + t];
                    cta[t] = v1 * fmaf(v1, a2fa, -b2a);
                    ctb[t] = v2 * fmaf(v2, a2fb, -b2b);
                }
                // keep/send transpose-butterfly per o (dual, interleaved) on
                // the DS pipe, then pc-preserving xor4/xor8 -> full 16-lane
                // p-sum for vote i0+4j+pc in every lane of the row.
                const float k01a = pb0 ? cta[1] : cta[0];
                const float s01a = pb0 ? cta[0] : cta[1];
                const float k23a = pb0 ? cta[3] : cta[2];
                const float s23a = pb0 ? cta[2] : cta[3];
                const float k01b = pb0 ? ctb[1] : ctb[0];
                const float s01b = pb0 ? ctb[0] : ctb[1];
                const float k23b = pb0 ? ctb[3] : ctb[2];
                const float s23b = pb0 ? ctb[2] : ctb[3];
                const float a01a = k01a + swz_xor1(s01a);
                const float a23a = k23a + swz_xor1(s23a);
                const float a01b = k01b + swz_xor1(s01b);
                const float a23b = k23b + swz_xor1(s23b);
                const float kka = pb1 ? a23a : a01a;
                const float ssa = pb1 ? a01a : a23a;
                const float kkb = pb1 ? a23b : a01b;
                const float ssb = pb1 ? a01b : a23b;
                const float qa = kka + swz_xor2(ssa);
                const float qb = kkb + swz_xor2(ssb);
                float fsa = qa + swz_xor4(qa);
                float fsb = qb + swz_xor4(qb);
                fsa += swz_xor8(fsa);
                fsb += swz_xor8(fsb);
                if (pr == (j & 3)) {
                    s_q[(i0 + 4 * j + pc) * QS + oa] = fsa;
                    s_q[(i0 + 4 * j + pc) * QS + ob] = fsb;
                }
            }
            __syncthreads();
            // ---- shared softmax over o per i: 576 items on 512 threads ----
            // item layout keeps quads aligned: 4 consecutive tids = same si.
            #pragma unroll
            for (int pass = 0; pass < 2; ++pass) {
                const int item = tid + pass * 512;
                if (pass == 0 || tid < 64) {     // quad-uniform predicate
                    const int si = item >> 2, sj = item & 3;
                    const float4 qv = *reinterpret_cast<const float4*>(&s_q[si * QS + sj * 4]);
                    float zz[4];
                    zz[0] = s_Lo[sj * 4 + 0] - qv.x;
                    zz[1] = s_Lo[sj * 4 + 1] - qv.y;
                    zz[2] = s_Lo[sj * 4 + 2] - qv.z;
                    zz[3] = s_Lo[sj * 4 + 3] - qv.w;
                    float m = fmaxf(fmaxf(zz[0], zz[1]), fmaxf(zz[2], zz[3]));
                    m = quad_max(m);
                    const float e0 = fexp2(zz[0] - m), e1 = fexp2(zz[1] - m);
                    const float e2 = fexp2(zz[2] - m), e3 = fexp2(zz[3] - m);
                    const float s = quad_sum(e0 + e1 + e2 + e3);
                    const float sc = s_iact[si] * frcp(s);
                    s_zr[(sj * 4 + 0) * RT + si] = e0 * sc;
                    s_zr[(sj * 4 + 1) * RT + si] = e1 * sc;
                    s_zr[(sj * 4 + 2) * RT + si] = e2 * sc;
                    s_zr[(sj * 4 + 3) * RT + si] = e3 * sc;
                }
            }
            __syncthreads();
        }
    }

    // ---- outputs (both o's) ----
    if (c == 0) {
        out[n * 256 + oa * 16 + p] = mean_a;
        out[n * 256 + ob * 16 + p] = mean_b;
    }
    if (lane == 0) {
        out[8 * 12 * 12 * 256 + n * 16 + oa] = oact_a;
        out[8 * 12 * 12 * 256 + n * 16 + ob] = oact_b;
    }
}

extern "C" void kernel_launch(void* const* d_in, const int* in_sizes, int n_in,
                              void* d_out, int out_size, void* d_ws, size_t ws_size,
                              hipStream_t stream) {
    const float* pose = (const float*)d_in[0];
    const float* act  = (const float*)d_in[1];
    const float* w    = (const float*)d_in[2];
    const float* bv   = (const float*)d_in[3];
    const float* ba   = (const float*)d_in[4];
    float* out = (float*)d_out;

    const size_t wt_bytes = size_t(I) * 256 * sizeof(float);   // 147456
    if (ws_size >= wt_bytes) {
        float* wt = (float*)d_ws;
        transpose_w_kernel<<<dim3(I), dim3(256), 0, stream>>>(w, wt);
        capsule_em_kernel<true><<<dim3(1152), dim3(512), 0, stream>>>(pose, act, wt, bv, ba, out);
    } else {
        capsule_em_kernel<false><<<dim3(1152), dim3(512), 0, stream>>>(pose, act, w, bv, ba, out);
    }
}

// Round 16
// 106.878 us; speedup vs baseline: 1.0651x; 1.0651x over previous
//
#include <hip/hip_runtime.h>

#define EPSF 1e-9f

constexpr int I   = 144;    // 9*16 input capsules
constexpr int IC  = 36;     // i's per chunk (4 chunks per wave)
constexpr int RT  = 148;    // s_zr row stride (144 + 4 pad)
constexpr int SP  = 20;     // s_pose row stride (16 + 4 pad)
constexpr int QS  = 20;     // s_q row stride (16 o's + 4 pad)

// Intra-quad reductions on the VALU pipe (DPP quad_perm), NOT the DS pipe.
// 0xB1 = quad_perm [1,0,3,2] (xor 1), 0x4E = quad_perm [2,3,0,1] (xor 2).
// 0x124 = row_ror:4, 0x128 = row_ror:8 (rows are 16 lanes on gfx9/CDNA).
// R20 CONFIRMED THIS IS OPTIMAL: ds_swizzle versions of these (DS pipe,
// -1 VALU inst/site) regressed 53.2->66.6us (+25%), VALUBusy 71->58%. DS
// latency (~27cy) lands on the serial reduction chains and even 8 waves/SIMD
// cannot hide it (all waves stall at the same points). DPP is single-cycle
// VALU; keep it. The R11 "DPP not DS" rule is regime-INDEPENDENT.
__device__ __forceinline__ float dpp_xor1(float x) {
    return __int_as_float(__builtin_amdgcn_update_dpp(0, __float_as_int(x), 0xB1, 0xF, 0xF, true));
}
__device__ __forceinline__ float dpp_xor2(float x) {
    return __int_as_float(__builtin_amdgcn_update_dpp(0, __float_as_int(x), 0x4E, 0xF, 0xF, true));
}
__device__ __forceinline__ float dpp_ror4(float x) {
    return __int_as_float(__builtin_amdgcn_update_dpp(0, __float_as_int(x), 0x124, 0xF, 0xF, true));
}
__device__ __forceinline__ float dpp_ror8(float x) {
    return __int_as_float(__builtin_amdgcn_update_dpp(0, __float_as_int(x), 0x128, 0xF, 0xF, true));
}
__device__ __forceinline__ float quad_sum(float x) {
    float y = x + dpp_xor1(x);
    return y + dpp_xor2(y);
}
__device__ __forceinline__ float quad_max(float x) {
    float y = fmaxf(x, dpp_xor1(x));
    return fmaxf(y, dpp_xor2(y));
}
// Full sum across the 16-lane row, entirely on VALU.
__device__ __forceinline__ float row_sum16(float x) {
    float y = quad_sum(x);
    y += dpp_ror4(y);
    return y + dpp_ror8(y);
}
// Cross-chunk sums on the VALU pipe (gfx950 permlane*_swap); shfl fallback.
__device__ __forceinline__ float add_xor16(float x) {
#if __has_builtin(__builtin_amdgcn_permlane16_swap)
    auto r = __builtin_amdgcn_permlane16_swap(__float_as_int(x), __float_as_int(x), false, false);
    return __int_as_float(r[0]) + __int_as_float(r[1]);
#else
    return x + __shfl_xor(x, 16);
#endif
}
__device__ __forceinline__ float add_xor32(float x) {
#if __has_builtin(__builtin_amdgcn_permlane32_swap)
    auto r = __builtin_amdgcn_permlane32_swap(__float_as_int(x), __float_as_int(x), false, false);
    return __int_as_float(r[0]) + __int_as_float(r[1]);
#else
    return x + __shfl_xor(x, 32);
#endif
}
// Fast 1/x (v_rcp_f32, ~1 ulp): fine under the 2e-2 absmax threshold.
__device__ __forceinline__ float frcp(float x) { return __builtin_amdgcn_rcpf(x); }
// Raw hardware log2/exp2; EM runs in base-2 domain (ln2 folded once).
__device__ __forceinline__ float flog2(float x) {
#if __has_builtin(__builtin_amdgcn_logf)
    return __builtin_amdgcn_logf(x);
#else
    return __log2f(x);
#endif
}
__device__ __forceinline__ float fexp2(float x) {
#if __has_builtin(__builtin_amdgcn_exp2f)
    return __builtin_amdgcn_exp2f(x);
#else
    return exp2f(x);
#endif
}

#define LN2F     0.69314718056f
#define INV_LN2F 1.44269504089f

// wt[i,o,pc,q] = w[i,o,q,pc]  -> vote loop reads one float4 per (i, lane)
__global__ void transpose_w_kernel(const float* __restrict__ w, float* __restrict__ wt) {
    const int i = blockIdx.x;
    const int t = threadIdx.x;                  // t = o*16 + q*4 + pc
    const float val = w[i * 256 + t];
    const int o = t >> 4, q = (t >> 2) & 3, pc = t & 3;
    wt[i * 256 + o * 16 + pc * 4 + q] = val;
}

// BANKED BEST (measured 53.2us dispatch / 108.6us bench, absmax 4.9e-4,
// reproduced R9/R14): 512 thd = 8 waves; wave owns o and o+8; dual ILP chains;
// 64 VGPR (8 waves/SIMD) + small spill (~11MB scratch) -> fastest.
// LAW (R15/R16): dur ~ 1/waves-per-SIMD; winning regime is VGPR <= 64; the
// small spill is the correct trade. Occupancy counter unreliable; trust
// VGPR_Count + dur. Residency is maxed (32 waves/CU, 133KB LDS < 160).
// Issue model: ~37.5us floor at 100% VALU busy; measured 53.2 at 71% busy.
// The ~29% idle is serial-chain latency (DPP ladders + transcendentals),
// already mostly covered by 8-deep wave multiplexing.
// REFUTED (do not retry — all with counter evidence):
//  - LDS-residency gating (R4/R5) / 64KB LDS window (R5)
//  - redundant per-wave softmax to cut barriers (R7: +46%)
//  - no-spill high-VGPR, launch_bounds (512,2) (R16: 6 w/SIMD, +26%)
//  - f16 vote packing (R17: hoisted unpacks, 45MB scratch, +33%)
//  - fused log-sigmoid (R18: CORRECTNESS absmax 0.5 — the eps-clamp in
//    log(sigmoid+1e-9) saturates deeply-negative logits, tying inactive
//    o's; keep exact sigmoid + flog2(o_act + EPSF))
//  - ds_swizzle cross-lane (R20: +25%, VALUBusy 71->58 — DS latency on
//    serial chains is unhidable; DPP rule is regime-independent)
// NOTE (R5): no barrier between vote loop and EM loop (stagger!).
// NOTE (R8): keep the 3-iter EM loop ROLLED (unroll 1) - I-fetch.
// NOTE (R7/R10): fp32 pk-packing neutral-to-negative. Keep scalar + DPP.
template <bool USE_WT>
__global__ __launch_bounds__(512, 4)
void capsule_em_kernel(const float* __restrict__ pose_in,   // [8,14,14,256]
                       const float* __restrict__ act_in,    // [8,14,14,16]
                       const float* __restrict__ wmat,      // wt (transposed) or w
                       const float* __restrict__ beta_v,    // [16]
                       const float* __restrict__ beta_a,    // [16]
                       float* __restrict__ out)             // pose 294912 | act 18432
{
    __shared__ __align__(16) float s_pose[I * SP];   // 11520 B
    __shared__ __align__(16) float s_zr[16 * RT];    //  9472 B  rr' [o][i]
    __shared__ __align__(16) float s_q[I * QS];      // 11520 B  full p-sums [i][o]
    __shared__ __align__(16) float s_iact[I + 4];    //   592 B
    __shared__ float s_Lo[16];                       //    64 B

    const int tid  = threadIdx.x;
    const int wv   = tid >> 6;          // wave id 0..7
    const int lane = tid & 63;
    const int oa   = wv;                // first owned o
    const int ob   = wv + 8;            // second owned o
    const int c    = lane >> 4;
    const int p    = lane & 15;
    const int pr   = p >> 2;
    const int pc   = p & 3;
    const int i0   = c * IC;
    const bool pb0 = pc & 1;
    const bool pb1 = pc & 2;

    const int n   = blockIdx.x;
    const int b   = n / 144;
    const int rem = n - b * 144;
    const int hp  = rem / 12;
    const int wp  = rem - hp * 12;

    // ---- stage pose patch (576 float4) + i_act (144 floats), 512 threads ----
    {
        const int t0 = tid;             // pass 1: all 512
        const int pk = t0 >> 6, l6 = t0 & 63;
        const int ki = pk / 3, kj = pk - ki * 3;
        const float4 val = *reinterpret_cast<const float4*>(
            &pose_in[((b * 14 + hp + ki) * 14 + (wp + kj)) * 256 + l6 * 4]);
        const int i = pk * 16 + (l6 >> 2), e = (l6 & 3) * 4;
        *reinterpret_cast<float4*>(&s_pose[i * SP + e]) = val;
    }
    if (tid < 64) {                     // pass 2: t = tid + 512
        const int t1 = tid + 512;
        const int pk = t1 >> 6, l6 = t1 & 63;
        const int ki = pk / 3, kj = pk - ki * 3;
        const float4 val = *reinterpret_cast<const float4*>(
            &pose_in[((b * 14 + hp + ki) * 14 + (wp + kj)) * 256 + l6 * 4]);
        const int i = pk * 16 + (l6 >> 2), e = (l6 & 3) * 4;
        *reinterpret_cast<float4*>(&s_pose[i * SP + e]) = val;
    }
    if (tid < 144) {
        const int pk = tid >> 4, ic = tid & 15;
        const int ki = pk / 3, kj = pk - ki * 3;
        s_iact[tid] = act_in[((b * 14 + hp + ki) * 14 + (wp + kj)) * 16 + ic];
    }
    __syncthreads();

    // ---- votes for BOTH o's: pose read shared ----
    float va[IC], vb[IC];
    #pragma unroll
    for (int ii = 0; ii < IC; ++ii) {
        const int i = i0 + ii;
        const float4 pv = *reinterpret_cast<const float4*>(&s_pose[i * SP + pr * 4]);
        if (USE_WT) {
            const float4 wa = *reinterpret_cast<const float4*>(&wmat[i * 256 + oa * 16 + pc * 4]);
            const float4 wb = *reinterpret_cast<const float4*>(&wmat[i * 256 + ob * 16 + pc * 4]);
            va[ii] = pv.x * wa.x + pv.y * wa.y + pv.z * wa.z + pv.w * wa.w;
            vb[ii] = pv.x * wb.x + pv.y * wb.y + pv.z * wb.z + pv.w * wb.w;
        } else {
            const float* wba = &wmat[i * 256 + oa * 16 + pc];
            const float* wbb = &wmat[i * 256 + ob * 16 + pc];
            va[ii] = pv.x * wba[0] + pv.y * wba[4] + pv.z * wba[8] + pv.w * wba[12];
            vb[ii] = pv.x * wbb[0] + pv.y * wbb[4] + pv.z * wbb[8] + pv.w * wbb[12];
        }
    }
    // NO barrier here (R5 lesson): waves enter the EM loop staggered.

    const float bva = beta_v[oa], bvb = beta_v[ob];
    const float baa = beta_a[oa], bab = beta_a[ob];

    float mean_a = 0.0f, mean_b = 0.0f, oact_a = 0.0f, oact_b = 0.0f;

    #pragma unroll 1
    for (int it = 0; it < 3; ++it) {
        // -------- M-step: two independent chains, interleaved for ILP --------
        float aSa = 0.0f, a1a = 0.0f, a2a = 0.0f;
        float aSb = 0.0f, a1b = 0.0f, a2b = 0.0f;
        const float* rra = (it == 0) ? &s_iact[i0] : &s_zr[oa * RT + i0];
        const float* rrb = (it == 0) ? &s_iact[i0] : &s_zr[ob * RT + i0];
        #pragma unroll
        for (int jj = 0; jj < 9; ++jj) {
            const float4 r4a = *reinterpret_cast<const float4*>(&rra[jj * 4]);
            const float4 r4b = *reinterpret_cast<const float4*>(&rrb[jj * 4]);
            const float ra[4] = {r4a.x, r4a.y, r4a.z, r4a.w};
            const float rb[4] = {r4b.x, r4b.y, r4b.z, r4b.w};
            #pragma unroll
            for (int k = 0; k < 4; ++k) {
                const float ta = ra[k] * va[jj * 4 + k];
                const float tb = rb[k] * vb[jj * 4 + k];
                aSa += ra[k];  a1a += ta;  a2a += ta * va[jj * 4 + k];
                aSb += rb[k];  a1b += tb;  a2b += tb * vb[jj * 4 + k];
            }
        }
        // cross-chunk sums on the VALU pipe; dual chains interleave
        aSa = add_xor16(aSa); aSb = add_xor16(aSb);
        a1a = add_xor16(a1a); a1b = add_xor16(a1b);
        a2a = add_xor16(a2a); a2b = add_xor16(a2b);
        aSa = add_xor32(aSa); aSb = add_xor32(aSb);
        a1a = add_xor32(a1a); a1b = add_xor32(a1b);
        a2a = add_xor32(a2a); a2b = add_xor32(a2b);
        if (it == 0) {   // iter-0 rr' = iact/16: fold 1/16 after reduction
            aSa *= 0.0625f; a1a *= 0.0625f; a2a *= 0.0625f;
            aSb *= 0.0625f; a1b *= 0.0625f; a2b *= 0.0625f;
        }

        const float inva = frcp(aSa + EPSF);
        const float invb = frcp(aSb + EPSF);
        mean_a = a1a * inva;
        mean_b = a1b * invb;
        float vara = (a2a - 2.0f * mean_a * a1a + mean_a * mean_a * aSa) * inva;
        float varb = (a2b - 2.0f * mean_b * a1b + mean_b * mean_b * aSb) * invb;
        vara = fmaxf(vara, 0.0f);
        varb = fmaxf(varb, 0.0f);
        // log(sigma+1e-9) == 0.5*log(var+1e-18) -> no sqrt. LOG2 domain.
        const float sl2a = row_sum16(0.5f * flog2(vara + 1e-18f));
        const float sl2b = row_sum16(0.5f * flog2(varb + 1e-18f));

        const float csa = aSa * (16.0f * bva + LN2F * sl2a);
        const float csb = aSb * (16.0f * bvb + LN2F * sl2b);
        const float it2 = INV_LN2F * (1.0f + (float)it);
        oact_a = frcp(1.0f + fexp2(-it2 * (baa - csa)));
        oact_b = frcp(1.0f + fexp2(-it2 * (bab - csb)));

        // ---------------- E-step (skip on last iter) ----------------
        if (it < 2) {
            const float a2fa = INV_LN2F * frcp(2.0f * vara + EPSF);
            const float a2fb = INV_LN2F * frcp(2.0f * varb + EPSF);
            const float b2a  = 2.0f * mean_a * a2fa;
            const float b2b  = 2.0f * mean_b * a2fb;
            const float cqa  = row_sum16(mean_a * mean_a * a2fa);
            const float cqb  = row_sum16(mean_b * mean_b * a2fb);
            const float LoA  = flog2(oact_a + EPSF) - sl2a - cqa;
            const float LoB  = flog2(oact_b + EPSF) - sl2b - cqb;
            if (lane == 0) { s_Lo[oa] = LoA; s_Lo[ob] = LoB; }
            #pragma unroll
            for (int j = 0; j < 9; ++j) {
                float cta[4], ctb[4];
                #pragma unroll
                for (int t = 0; t < 4; ++t) {
                    const float v1 = va[4 * j + t];
                    const float v2 = vb[4 * j + t];
                    cta[t] = v1 * fmaf(v1, a2fa, -b2a);
                    ctb[t] = v2 * fmaf(v2, a2fb, -b2b);
                }
                // keep/send transpose-butterfly per o (dual, interleaved),
                // then pc-preserving ror4/ror8 -> full 16-lane p-sum.
                const float k01a = pb0 ? cta[1] : cta[0];
                const float s01a = pb0 ? cta[0] : cta[1];
                const float k23a = pb0 ? cta[3] : cta[2];
                const float s23a = pb0 ? cta[2] : cta[3];
                const float k01b = pb0 ? ctb[1] : ctb[0];
                const float s01b = pb0 ? ctb[0] : ctb[1];
                const float k23b = pb0 ? ctb[3] : ctb[2];
                const float s23b = pb0 ? ctb[2] : ctb[3];
                const float a01a = k01a + dpp_xor1(s01a);
                const float a23a = k23a + dpp_xor1(s23a);
                const float a01b = k01b + dpp_xor1(s01b);
                const float a23b = k23b + dpp_xor1(s23b);
                const float kka = pb1 ? a23a : a01a;
                const float ssa = pb1 ? a01a : a23a;
                const float kkb = pb1 ? a23b : a01b;
                const float ssb = pb1 ? a01b : a23b;
                const float qa = kka + dpp_xor2(ssa);
                const float qb = kkb + dpp_xor2(ssb);
                float fsa = qa + dpp_ror4(qa);
                float fsb = qb + dpp_ror4(qb);
                fsa += dpp_ror8(fsa);
                fsb += dpp_ror8(fsb);
                if (pr == (j & 3)) {
                    s_q[(i0 + 4 * j + pc) * QS + oa] = fsa;
                    s_q[(i0 + 4 * j + pc) * QS + ob] = fsb;
                }
            }
            __syncthreads();
            // ---- shared softmax over o per i: 576 items on 512 threads ----
            // item layout keeps quads aligned: 4 consecutive tids = same si.
            #pragma unroll
            for (int pass = 0; pass < 2; ++pass) {
                const int item = tid + pass * 512;
                if (pass == 0 || tid < 64) {     // quad-uniform predicate
                    const int si = item >> 2, sj = item & 3;
                    const float4 qv = *reinterpret_cast<const float4*>(&s_q[si * QS + sj * 4]);
                    float zz[4];
                    zz[0] = s_Lo[sj * 4 + 0] - qv.x;
                    zz[1] = s_Lo[sj * 4 + 1] - qv.y;
                    zz[2] = s_Lo[sj * 4 + 2] - qv.z;
                    zz[3] = s_Lo[sj * 4 + 3] - qv.w;
                    float m = fmaxf(fmaxf(zz[0], zz[1]), fmaxf(zz[2], zz[3]));
                    m = quad_max(m);
                    const float e0 = fexp2(zz[0] - m), e1 = fexp2(zz[1] - m);
                    const float e2 = fexp2(zz[2] - m), e3 = fexp2(zz[3] - m);
                    const float s = quad_sum(e0 + e1 + e2 + e3);
                    const float sc = s_iact[si] * frcp(s);
                    s_zr[(sj * 4 + 0) * RT + si] = e0 * sc;
                    s_zr[(sj * 4 + 1) * RT + si] = e1 * sc;
                    s_zr[(sj * 4 + 2) * RT + si] = e2 * sc;
                    s_zr[(sj * 4 + 3) * RT + si] = e3 * sc;
                }
            }
            __syncthreads();
        }
    }

    // ---- outputs (both o's) ----
    if (c == 0) {
        out[n * 256 + oa * 16 + p] = mean_a;
        out[n * 256 + ob * 16 + p] = mean_b;
    }
    if (lane == 0) {
        out[8 * 12 * 12 * 256 + n * 16 + oa] = oact_a;
        out[8 * 12 * 12 * 256 + n * 16 + ob] = oact_b;
    }
}

extern "C" void kernel_launch(void* const* d_in, const int* in_sizes, int n_in,
                              void* d_out, int out_size, void* d_ws, size_t ws_size,
                              hipStream_t stream) {
    const float* pose = (const float*)d_in[0];
    const float* act  = (const float*)d_in[1];
    const float* w    = (const float*)d_in[2];
    const float* bv   = (const float*)d_in[3];
    const float* ba   = (const float*)d_in[4];
    float* out = (float*)d_out;

    const size_t wt_bytes = size_t(I) * 256 * sizeof(float);   // 147456
    if (ws_size >= wt_bytes) {
        float* wt = (float*)d_ws;
        transpose_w_kernel<<<dim3(I), dim3(256), 0, stream>>>(w, wt);
        capsule_em_kernel<true><<<dim3(1152), dim3(512), 0, stream>>>(pose, act, wt, bv, ba, out);
    } else {
        capsule_em_kernel<false><<<dim3(1152), dim3(512), 0, stream>>>(pose, act, w, bv, ba, out);
    }
}